// Round 8
// baseline (166.577 us; speedup 1.0000x reference)
//
#include <hip/hip_runtime.h>
#include <hip/hip_bf16.h>

typedef __attribute__((ext_vector_type(8))) short short8;
typedef __attribute__((ext_vector_type(4))) float f32x4;

#define B_T 200
#define B_D 128

static __device__ __forceinline__ short f2bf(float f) {
  // round-to-nearest-even f32 -> bf16 (inputs are finite)
  unsigned u = __builtin_bit_cast(unsigned, f);
  u += 0x7fffu + ((u >> 16) & 1u);
  return (short)(u >> 16);
}
static __device__ __forceinline__ short8 cvt8(f32x4 a, f32x4 b) {
  short8 t;
  t[0] = f2bf(a[0]); t[1] = f2bf(a[1]); t[2] = f2bf(a[2]); t[3] = f2bf(a[3]);
  t[4] = f2bf(b[0]); t[5] = f2bf(b[1]); t[6] = f2bf(b[2]); t[7] = f2bf(b[3]);
  return t;
}

// 256 threads / 4 waves, launch_bounds(256,4): the 2nd arg acts as an exact
// waves-per-EU clamp (R5/R6 evidence) -> 4 waves/EU = 16 waves/CU = FOUR
// independent 4-wave blocks resident (vs two 8-wave blocks in R2/R7).
// VGPR cap stays 512/4 = 128 (~90 demand -> no spill). LDS ~34.4 KB -> 4
// blocks fit in 160 KB.
__global__ __launch_bounds__(256, 4)
void ta_fused(const float* __restrict__ x,      // [B,T,D]
              const float* __restrict__ cand,   // [B,D]
              const void*  __restrict__ maskp,  // [B,T] int32 or 1-byte bool
              const float* __restrict__ W1,     // [384,128]
              const float* __restrict__ b1,     // [128]
              const float* __restrict__ ap,     // [1]
              const float* __restrict__ W2,     // [128]
              const float* __restrict__ b2p,    // [1] (unused: softmax shift-invariant)
              float* __restrict__ out)          // [B,D]
{
  // wbt fragment-linear bf16: element (k,j) at ((k>>3)*128 + j)*8 + (k&7).
  __shared__ __align__(16) short wbt[B_D * B_D];   // 32 KB
  __shared__ float part[2][B_D];   // beta halves; reused for phase-C partials
  __shared__ float w2_lds[B_D];
  __shared__ float scores[208];
  __shared__ float red[8];

  const int b    = blockIdx.x;
  const int tid  = threadIdx.x;
  const int lane = tid & 63;
  const int wv   = tid >> 6;      // 0..3
  const int l15  = lane & 15;
  const int g    = lane >> 4;     // 0..3

  // ---- mask dtype probe: every wave scans the SAME 512 B -> block-consistent,
  // no LDS, no barrier. int32 storage has all off-aligned bytes == 0.
  int flag1b;
  {
    const unsigned char* mb = (const unsigned char*)maskp;
    unsigned long long v8 = *(const unsigned long long*)(mb + lane * 8);
    flag1b = __any((v8 & 0xFFFFFF00FFFFFF00ull) != 0ull);
  }
  // hoist this block's mask row (off the softmax critical path)
  bool mk = false;
  if (tid < B_T) {
    if (flag1b) mk = ((const unsigned char*)maskp)[(size_t)b * B_T + tid] != 0;
    else        mk = ((const int*)maskp)[(size_t)b * B_T + tid] != 0;
  }

  if (tid < B_D) w2_lds[tid] = W2[tid];

  // ---- phase 1: Wb = W1a + c (*) W1c -> wbt ; beta halves -> part
  const float* cb = cand + (size_t)b * B_D;
  {
    const int j = tid & 127;          // fixed per thread (256 % 128 == 0)
    const int h = tid >> 7;           // 0..1
    // each thread produces 8 k-octets for its j: one ds_write_b128 at
    // consecutive-lane addresses -> conflict-free.
    #pragma unroll 2
    for (int it = 0; it < 8; ++it) {
      const int ko = it * 2 + h;      // 0..15
      const int k0 = ko * 8;
      short8 t;
      #pragma unroll
      for (int e = 0; e < 8; ++e) {
        float c  = cb[k0 + e];
        float wa = W1[(size_t)(k0 + e) * B_D + j];
        float wc = W1[(size_t)(256 + k0 + e) * B_D + j];
        t[e] = f2bf(wa + c * wc);
      }
      *(short8*)&wbt[(ko * B_D + j) * 8] = t;
    }
    // part[h][j] = (h==0 ? b1[j] : 0) + sum_{k in h-half} c[k]*W1b[k][j]
    float s = (h == 0) ? b1[j] : 0.f;
    const float* w1b = W1 + (size_t)(B_D + h * 64) * B_D + j;
    #pragma unroll 4
    for (int k = 0; k < 64; ++k) s += cb[h * 64 + k] * w1b[(size_t)k * B_D];
    part[h][j] = s;
  }
  __syncthreads();   // the ONLY barrier before MFMA

  float betaL[8], w2L[8];
  #pragma unroll
  for (int nt = 0; nt < 8; ++nt) {
    int col = nt * 16 + l15;
    betaL[nt] = part[0][col] + part[1][col];
    w2L[nt]   = w2_lds[col];
  }
  const float alpha = ap[0];

  // ---- phase A: per-tile {load x, cvt, MFMA, PReLU+W2 epilogue} -> scores.
  // x tile is RELEASED after use (re-read in phase C from L2/L3) -> low regs.
#define TILE_SCORE(MT) do {                                                   \
    int row = (MT) * 16 + l15; if (row > B_T - 1) row = B_T - 1;              \
    const float* xr = x + ((size_t)b * B_T + row) * B_D + g * 8;              \
    f32x4 p0 = *(const f32x4*)(xr +  0), p1 = *(const f32x4*)(xr +   4);      \
    f32x4 p2 = *(const f32x4*)(xr + 32), p3 = *(const f32x4*)(xr +  36);      \
    f32x4 p4 = *(const f32x4*)(xr + 64), p5 = *(const f32x4*)(xr +  68);      \
    f32x4 p6 = *(const f32x4*)(xr + 96), p7 = *(const f32x4*)(xr + 100);      \
    short8 a0 = cvt8(p0, p1), a1 = cvt8(p2, p3);                              \
    short8 a2 = cvt8(p4, p5), a3 = cvt8(p6, p7);                              \
    float sc[4] = {0.f, 0.f, 0.f, 0.f};                                       \
    _Pragma("unroll")                                                         \
    for (int nt = 0; nt < 8; ++nt) {                                          \
      f32x4 acc = {0.f, 0.f, 0.f, 0.f};                                       \
      const short8* wp = (const short8*)wbt + g * B_D + nt * 16 + l15;        \
      acc = __builtin_amdgcn_mfma_f32_16x16x32_bf16(a0, wp[0],    acc, 0,0,0);\
      acc = __builtin_amdgcn_mfma_f32_16x16x32_bf16(a1, wp[512],  acc, 0,0,0);\
      acc = __builtin_amdgcn_mfma_f32_16x16x32_bf16(a2, wp[1024], acc, 0,0,0);\
      acc = __builtin_amdgcn_mfma_f32_16x16x32_bf16(a3, wp[1536], acc, 0,0,0);\
      _Pragma("unroll")                                                       \
      for (int r = 0; r < 4; ++r) {                                           \
        float h = acc[r] + betaL[nt];                                         \
        float p = (h >= 0.f) ? h : alpha * h;                                 \
        sc[r] += p * w2L[nt];                                                 \
      }                                                                       \
    }                                                                         \
    _Pragma("unroll")                                                         \
    for (int r = 0; r < 4; ++r) {                                             \
      float v = sc[r];                                                        \
      v += __shfl_xor(v, 1, 16); v += __shfl_xor(v, 2, 16);                   \
      v += __shfl_xor(v, 4, 16); v += __shfl_xor(v, 8, 16);                   \
      if (l15 == 0) scores[(MT) * 16 + g * 4 + r] = v;                        \
    }                                                                         \
  } while (0)

  // 13 m-tiles over 4 waves: wave w -> {w, 4+w, 8+w}, wave 0 also 12.
  TILE_SCORE(wv);
  TILE_SCORE(4 + wv);
  TILE_SCORE(8 + wv);
  if (wv == 0) TILE_SCORE(12);
#undef TILE_SCORE
  __syncthreads();

  // ---- phase B: masked softmax over t (b2 omitted: softmax shift-invariant)
  {
    float s = (tid < B_T && mk) ? scores[tid] : -INFINITY;
    float v = s;
    #pragma unroll
    for (int m = 32; m >= 1; m >>= 1) v = fmaxf(v, __shfl_xor(v, m, 64));
    if (lane == 0) red[wv] = v;
    __syncthreads();
    float mx = fmaxf(fmaxf(red[0], red[1]), fmaxf(red[2], red[3]));
    float e = mk ? __expf(s - mx) : 0.f;
    float sv = e;
    #pragma unroll
    for (int m = 32; m >= 1; m >>= 1) sv += __shfl_xor(sv, m, 64);
    if (lane == 0) red[4 + wv] = sv;
    __syncthreads();
    float Z = red[4] + red[5] + red[6] + red[7];
    if (tid < 208) scores[tid] = e / Z;    // tid in [200,208): e==0 -> 0
  }
  __syncthreads();

  // ---- phase C: out[b,:] = sum_t w[t]*x[t,:], re-reading x (L2/L3-hot).
  // thread (h = tid>>7, d = tid&127) accumulates t in [h*100, h*100+100).
  {
    const int d = tid & 127;
    const int h = tid >> 7;
    const float* xc = x + ((size_t)b * B_T + h * 100) * B_D + d;
    float s = 0.f;
    #pragma unroll 5
    for (int t = 0; t < 100; ++t) s = fmaf(scores[h * 100 + t], xc[(size_t)t * B_D], s);
    __syncthreads();          // part's beta contents fully consumed earlier
    part[h][d] = s;
  }
  __syncthreads();
  if (tid < B_D) {
    out[(size_t)b * B_D + tid] = part[0][tid] + part[1][tid];
  }
}

extern "C" void kernel_launch(void* const* d_in, const int* in_sizes, int n_in,
                              void* d_out, int out_size, void* d_ws, size_t ws_size,
                              hipStream_t stream) {
  const float* x    = (const float*)d_in[0];
  const float* cand = (const float*)d_in[1];
  const void*  mask = d_in[2];
  const float* W1   = (const float*)d_in[3];
  const float* b1   = (const float*)d_in[4];
  const float* a    = (const float*)d_in[5];
  const float* W2   = (const float*)d_in[6];
  const float* b2   = (const float*)d_in[7];
  float* out = (float*)d_out;
  const int B = in_sizes[1] / B_D;   // candidate is [B,128]
  ta_fused<<<B, 256, 0, stream>>>(x, cand, mask, W1, b1, a, W2, b2, out);
}

// Round 9
// 147.669 us; speedup vs baseline: 1.1280x; 1.1280x over previous
//
#include <hip/hip_runtime.h>
#include <hip/hip_bf16.h>

typedef __attribute__((ext_vector_type(8))) short short8;
typedef __attribute__((ext_vector_type(4))) float f32x4;

#define B_T 200
#define B_D 128

static __device__ __forceinline__ short f2bf(float f) {
  // round-to-nearest-even f32 -> bf16 (inputs are finite)
  unsigned u = __builtin_bit_cast(unsigned, f);
  u += 0x7fffu + ((u >> 16) & 1u);
  return (short)(u >> 16);
}
static __device__ __forceinline__ short8 cvt8(f32x4 a, f32x4 b) {
  short8 t;
  t[0] = f2bf(a[0]); t[1] = f2bf(a[1]); t[2] = f2bf(a[2]); t[3] = f2bf(a[3]);
  t[4] = f2bf(b[0]); t[5] = f2bf(b[1]); t[6] = f2bf(b[2]); t[7] = f2bf(b[3]);
  return t;
}

// 256 threads / 4 waves, (256,4): 16 waves/CU, 4 independent blocks resident.
// VGPR cap 128 (~110 demand -> no spill). LDS 38.2 KB -> 4 blocks/CU.
__global__ __launch_bounds__(256, 4)
void ta_fused(const float* __restrict__ x,      // [B,T,D]
              const float* __restrict__ cand,   // [B,D]
              const void*  __restrict__ maskp,  // [B,T] int32 or 1-byte bool
              const float* __restrict__ W1,     // [384,128]
              const float* __restrict__ b1,     // [128]
              const float* __restrict__ ap,     // [1]
              const float* __restrict__ W2,     // [128]
              const float* __restrict__ b2p,    // [1] (unused: softmax shift-invariant)
              float* __restrict__ out)          // [B,D]
{
  // wbt fragment-linear bf16: element (k,j) at ((k>>3)*128 + j)*8 + (k&7).
  __shared__ __align__(16) short wbt[B_D * B_D];   // 32 KB
  __shared__ __align__(16) float part[8][B_D];     // beta halves (0..1); phase-C partials (0..7)
  __shared__ float w2_lds[B_D];
  __shared__ float scores[208];
  __shared__ float red[8];

  const int b    = blockIdx.x;
  const int tid  = threadIdx.x;
  const int lane = tid & 63;
  const int wv   = tid >> 6;      // 0..3
  const int l15  = lane & 15;
  const int g    = lane >> 4;     // 0..3

  // ---- mask dtype probe: every wave scans the SAME 512 B -> block-consistent,
  // no LDS, no barrier. int32 storage has all off-aligned bytes == 0.
  int flag1b;
  {
    const unsigned char* mb = (const unsigned char*)maskp;
    unsigned long long v8 = *(const unsigned long long*)(mb + lane * 8);
    flag1b = __any((v8 & 0xFFFFFF00FFFFFF00ull) != 0ull);
  }
  // hoist this block's mask row (off the softmax critical path)
  bool mk = false;
  if (tid < B_T) {
    if (flag1b) mk = ((const unsigned char*)maskp)[(size_t)b * B_T + tid] != 0;
    else        mk = ((const int*)maskp)[(size_t)b * B_T + tid] != 0;
  }

  if (tid < B_D) w2_lds[tid] = W2[tid];

  // ---- phase 1: Wb = W1a + c (*) W1c -> wbt ; beta halves -> part[0..1]
  const float* cb = cand + (size_t)b * B_D;
  {
    const int j = tid & 127;          // fixed per thread (256 % 128 == 0)
    const int h = tid >> 7;           // 0..1 (wave-uniform)
    // each thread produces 8 k-octets for its j: one ds_write_b128 at
    // consecutive-lane addresses -> conflict-free.
    #pragma unroll 2
    for (int it = 0; it < 8; ++it) {
      const int ko = it * 2 + h;      // 0..15
      const int k0 = ko * 8;
      short8 t;
      #pragma unroll
      for (int e = 0; e < 8; ++e) {
        float c  = cb[k0 + e];
        float wa = W1[(size_t)(k0 + e) * B_D + j];
        float wc = W1[(size_t)(256 + k0 + e) * B_D + j];
        t[e] = f2bf(wa + c * wc);
      }
      *(short8*)&wbt[(ko * B_D + j) * 8] = t;
    }
    // beta: 4 independent accumulators for MLP (strided L2 loads)
    float s0 = (h == 0) ? b1[j] : 0.f, s1 = 0.f, s2 = 0.f, s3 = 0.f;
    const float* w1b = W1 + (size_t)(B_D + h * 64) * B_D + j;
    #pragma unroll 8
    for (int k = 0; k < 64; k += 4) {
      s0 = fmaf(cb[h * 64 + k    ], w1b[(size_t)(k    ) * B_D], s0);
      s1 = fmaf(cb[h * 64 + k + 1], w1b[(size_t)(k + 1) * B_D], s1);
      s2 = fmaf(cb[h * 64 + k + 2], w1b[(size_t)(k + 2) * B_D], s2);
      s3 = fmaf(cb[h * 64 + k + 3], w1b[(size_t)(k + 3) * B_D], s3);
    }
    part[h][j] = (s0 + s1) + (s2 + s3);
  }
  __syncthreads();   // the ONLY barrier before MFMA

  float betaL[8], w2L[8];
  #pragma unroll
  for (int nt = 0; nt < 8; ++nt) {
    int col = nt * 16 + l15;
    betaL[nt] = part[0][col] + part[1][col];
    w2L[nt]   = w2_lds[col];
  }
  const float alpha = ap[0];

  // ---- phase A: per-tile {load x, cvt, MFMA, PReLU+W2 epilogue} -> scores.
  // x tile is RELEASED after use (re-read in phase C) -> low regs.
#define TILE_SCORE(MT) do {                                                   \
    int row = (MT) * 16 + l15; if (row > B_T - 1) row = B_T - 1;              \
    const float* xr = x + ((size_t)b * B_T + row) * B_D + g * 8;              \
    f32x4 p0 = *(const f32x4*)(xr +  0), p1 = *(const f32x4*)(xr +   4);      \
    f32x4 p2 = *(const f32x4*)(xr + 32), p3 = *(const f32x4*)(xr +  36);      \
    f32x4 p4 = *(const f32x4*)(xr + 64), p5 = *(const f32x4*)(xr +  68);      \
    f32x4 p6 = *(const f32x4*)(xr + 96), p7 = *(const f32x4*)(xr + 100);      \
    short8 a0 = cvt8(p0, p1), a1 = cvt8(p2, p3);                              \
    short8 a2 = cvt8(p4, p5), a3 = cvt8(p6, p7);                              \
    float sc[4] = {0.f, 0.f, 0.f, 0.f};                                       \
    _Pragma("unroll")                                                         \
    for (int nt = 0; nt < 8; ++nt) {                                          \
      f32x4 acc = {0.f, 0.f, 0.f, 0.f};                                       \
      const short8* wp = (const short8*)wbt + g * B_D + nt * 16 + l15;        \
      acc = __builtin_amdgcn_mfma_f32_16x16x32_bf16(a0, wp[0],    acc, 0,0,0);\
      acc = __builtin_amdgcn_mfma_f32_16x16x32_bf16(a1, wp[512],  acc, 0,0,0);\
      acc = __builtin_amdgcn_mfma_f32_16x16x32_bf16(a2, wp[1024], acc, 0,0,0);\
      acc = __builtin_amdgcn_mfma_f32_16x16x32_bf16(a3, wp[1536], acc, 0,0,0);\
      _Pragma("unroll")                                                       \
      for (int r = 0; r < 4; ++r) {                                           \
        float h = acc[r] + betaL[nt];                                         \
        float p = (h >= 0.f) ? h : alpha * h;                                 \
        sc[r] += p * w2L[nt];                                                 \
      }                                                                       \
    }                                                                         \
    _Pragma("unroll")                                                         \
    for (int r = 0; r < 4; ++r) {                                             \
      float v = sc[r];                                                        \
      v += __shfl_xor(v, 1, 16); v += __shfl_xor(v, 2, 16);                   \
      v += __shfl_xor(v, 4, 16); v += __shfl_xor(v, 8, 16);                   \
      if (l15 == 0) scores[(MT) * 16 + g * 4 + r] = v;                        \
    }                                                                         \
  } while (0)

  // 13 m-tiles over 4 waves: wave w -> {w, 4+w, 8+w}, wave 0 also 12.
  TILE_SCORE(wv);
  TILE_SCORE(4 + wv);
  TILE_SCORE(8 + wv);
  if (wv == 0) TILE_SCORE(12);
#undef TILE_SCORE
  __syncthreads();

  // ---- phase B: masked softmax, 2 barriers. scores <- UNNORMALIZED e;
  // the 1/Z divide happens once at the final output store.
  {
    float s = (tid < B_T && mk) ? scores[tid] : -INFINITY;
    float v = s;
    #pragma unroll
    for (int m = 32; m >= 1; m >>= 1) v = fmaxf(v, __shfl_xor(v, m, 64));
    if (lane == 0) red[wv] = v;
    __syncthreads();
    float mx = fmaxf(fmaxf(red[0], red[1]), fmaxf(red[2], red[3]));
    float e = mk ? __expf(s - mx) : 0.f;
    float sv = e;
    #pragma unroll
    for (int m = 32; m >= 1; m >>= 1) sv += __shfl_xor(sv, m, 64);
    if (lane == 0) red[4 + wv] = sv;
    if (tid < 208) scores[tid] = e;     // tid in [200,208): e==0
    __syncthreads();
  }

  // ---- phase C: part[p][:] = sum_{t in p-slice} e[t]*x[t,:].
  // thread (p = tid>>5, d4 = (tid&31)*4): contiguous f32x4 loads (coalesced),
  // 4-wide accumulator, 25 independent-address iterations -> high MLP.
  {
    const int d4 = (tid & 31) << 2;
    const int p  = tid >> 5;            // 0..7, t in [25p, 25p+25)
    const float* xc = x + ((size_t)b * B_T + p * 25) * B_D + d4;
    f32x4 acc = {0.f, 0.f, 0.f, 0.f};
    #pragma unroll 5
    for (int t = 0; t < 25; ++t) {
      f32x4 xv = *(const f32x4*)(xc + (size_t)t * B_D);
      float w = scores[p * 25 + t];
      acc[0] = fmaf(w, xv[0], acc[0]);
      acc[1] = fmaf(w, xv[1], acc[1]);
      acc[2] = fmaf(w, xv[2], acc[2]);
      acc[3] = fmaf(w, xv[3], acc[3]);
    }
    __syncthreads();    // beta contents of part[] fully consumed in betaL
    *(f32x4*)&part[p][d4] = acc;
  }
  __syncthreads();
  if (tid < B_D) {
    float Z = (red[4] + red[5]) + (red[6] + red[7]);
    float s = 0.f;
    #pragma unroll
    for (int p = 0; p < 8; ++p) s += part[p][tid];
    out[(size_t)b * B_D + tid] = s / Z;
  }
}

extern "C" void kernel_launch(void* const* d_in, const int* in_sizes, int n_in,
                              void* d_out, int out_size, void* d_ws, size_t ws_size,
                              hipStream_t stream) {
  const float* x    = (const float*)d_in[0];
  const float* cand = (const float*)d_in[1];
  const void*  mask = d_in[2];
  const float* W1   = (const float*)d_in[3];
  const float* b1   = (const float*)d_in[4];
  const float* a    = (const float*)d_in[5];
  const float* W2   = (const float*)d_in[6];
  const float* b2   = (const float*)d_in[7];
  float* out = (float*)d_out;
  const int B = in_sizes[1] / B_D;   // candidate is [B,128]
  ta_fused<<<B, 256, 0, stream>>>(x, cand, mask, W1, b1, a, W2, b2, out);
}